// Round 1
// baseline (109.480 us; speedup 1.0000x reference)
//
#include <hip/hip_runtime.h>
#include <hip/hip_bf16.h>
#include <stdint.h>

// QuantizedLinear: out[m][n] = (sum_k x[m][k]*W[n][k]) * scale + bias[n]
// M=256 (B*S), K=4096, N=11008. W int32 holding int8 values -> exact in bf16.
// Strategy: bf16 MFMA 16x16x32; scale applied in epilogue (exact W path).

#define M 256
#define N 11008
#define K 4096
#define BM 256
#define BN 32
#define BK 64
#define NKT (K / BK)   // 64

typedef __bf16 bf16x8 __attribute__((ext_vector_type(8)));
typedef float  f32x4  __attribute__((ext_vector_type(4)));

// ---- pass 1: x f32 -> bf16 into workspace ----
__global__ void cvt_x_kernel(const float* __restrict__ x, __bf16* __restrict__ xb) {
    int i = (blockIdx.x * 256 + threadIdx.x) * 4;
    float4 v = *(const float4*)(x + i);
    union { __bf16 b[4]; uint2 u; } o;
    o.b[0] = (__bf16)v.x; o.b[1] = (__bf16)v.y;
    o.b[2] = (__bf16)v.z; o.b[3] = (__bf16)v.w;
    *(uint2*)(xb + i) = o.u;
}

// ---- pass 2: GEMM ----
// block: 256 threads = 4 waves; wave w owns rows [w*64, w*64+64) x all 32 cols.
// LDS: A tile [256][64] bf16 (32KB) + B tile [32][64] bf16 (4KB), double buffered = 72KB.
// XOR swizzle within each 128B row: byte ^= (row&7)<<4  (2-way max conflict = free).
__global__ __launch_bounds__(256, 2) void qlin_gemm(
    const __bf16* __restrict__ xb, const int* __restrict__ w,
    const float* __restrict__ scale, const float* __restrict__ bias,
    float* __restrict__ out) {

    __shared__ uint4 smem4[(2 * BM * BK * 2 + 2 * BN * BK * 2) / 16];
    char* smem = (char*)smem4;
    char* Ab[2] = { smem, smem + BM * BK * 2 };
    char* Bb[2] = { smem + 2 * BM * BK * 2, smem + 2 * BM * BK * 2 + BN * BK * 2 };

    const int tid  = threadIdx.x;
    const int lane = tid & 63;
    const int wid  = tid >> 6;       // 0..3
    const int n0   = blockIdx.x * BN;

    f32x4 acc[4][2] = {};

    // --- A staging constants (global_load_lds, pre-swizzled source) ---
    // region r = wid*8 + j covers rows r*8..r*8+7; lane l -> row r*8+(l>>3), slot (l&7)*16.
    const int a_chunk_byte = ((lane & 7) * 16) ^ ((lane >> 3) << 4); // swizzled byte within 128B row window
    const __bf16* a_src0 = xb + (size_t)(wid * 64 + (lane >> 3)) * K + (a_chunk_byte >> 1);

    // --- B staging constants (reg-staged int32 -> bf16) ---
    const int brow = tid >> 3;   // 0..31
    const int bkc  = tid & 7;    // 0..7
    const int* wsrc0 = w + (size_t)(n0 + brow) * K + bkc * 8;
    const int bdst_off = brow * 128 + (((bkc * 16) ^ ((brow & 7) << 4)));

    auto issueA = [&](int buf, int kt) {
        const int k0 = kt * BK;
#pragma unroll
        for (int j = 0; j < 8; ++j) {
            const __bf16* src = a_src0 + (size_t)j * 8 * K + k0;
            char* dst = Ab[buf] + (wid * 8 + j) * 1024;
            __builtin_amdgcn_global_load_lds(
                (const __attribute__((address_space(1))) void*)src,
                (__attribute__((address_space(3))) void*)dst, 16, 0, 0);
        }
    };

    auto compute = [&](int buf) {
        const char* A = Ab[buf];
        const char* B = Bb[buf];
#pragma unroll
        for (int ks = 0; ks < 2; ++ks) {
            const int kb = ks * 64 + (lane >> 4) * 16;
            bf16x8 af[4], bfr[2];
#pragma unroll
            for (int fm = 0; fm < 4; ++fm) {
                const int row = wid * 64 + fm * 16 + (lane & 15);
                af[fm] = *(const bf16x8*)(A + row * 128 + (kb ^ ((row & 7) << 4)));
            }
#pragma unroll
            for (int fn = 0; fn < 2; ++fn) {
                const int row = fn * 16 + (lane & 15);
                bfr[fn] = *(const bf16x8*)(B + row * 128 + (kb ^ ((row & 7) << 4)));
            }
#pragma unroll
            for (int fm = 0; fm < 4; ++fm)
#pragma unroll
                for (int fn = 0; fn < 2; ++fn)
                    acc[fm][fn] = __builtin_amdgcn_mfma_f32_16x16x32_bf16(
                        af[fm], bfr[fn], acc[fm][fn], 0, 0, 0);
        }
    };

    // prologue: stage tile 0 fully
    issueA(0, 0);
    {
        const int* ws = wsrc0;
        int4 v0 = *(const int4*)ws;
        int4 v1 = *(const int4*)(ws + 4);
        union { __bf16 b[8]; bf16x8 v; } t;
        t.b[0]=(__bf16)(float)v0.x; t.b[1]=(__bf16)(float)v0.y;
        t.b[2]=(__bf16)(float)v0.z; t.b[3]=(__bf16)(float)v0.w;
        t.b[4]=(__bf16)(float)v1.x; t.b[5]=(__bf16)(float)v1.y;
        t.b[6]=(__bf16)(float)v1.z; t.b[7]=(__bf16)(float)v1.w;
        *(bf16x8*)(Bb[0] + bdst_off) = t.v;
    }
    __syncthreads();

    for (int kt = 0; kt < NKT; ++kt) {
        const int cur = kt & 1;
        const int nxt = cur ^ 1;
        int4 v0, v1;
        const bool pf = (kt + 1 < NKT);
        if (pf) {
            issueA(nxt, kt + 1);                    // async HBM->LDS, in flight during compute
            const int* ws = wsrc0 + (kt + 1) * BK;  // W loads to regs, in flight during compute
            v0 = *(const int4*)ws;
            v1 = *(const int4*)(ws + 4);
        }
        compute(cur);
        if (pf) {
            union { __bf16 b[8]; bf16x8 v; } t;
            t.b[0]=(__bf16)(float)v0.x; t.b[1]=(__bf16)(float)v0.y;
            t.b[2]=(__bf16)(float)v0.z; t.b[3]=(__bf16)(float)v0.w;
            t.b[4]=(__bf16)(float)v1.x; t.b[5]=(__bf16)(float)v1.y;
            t.b[6]=(__bf16)(float)v1.z; t.b[7]=(__bf16)(float)v1.w;
            *(bf16x8*)(Bb[nxt] + bdst_off) = t.v;
        }
        __syncthreads();
    }

    // epilogue: D layout col=lane&15, row=(lane>>4)*4+reg (m89)
    const float s = scale[0];
    const int ecol  = lane & 15;
    const int erow0 = (lane >> 4) * 4;
#pragma unroll
    for (int fn = 0; fn < 2; ++fn) {
        const int n = n0 + fn * 16 + ecol;
        const float bv = bias[n];
#pragma unroll
        for (int fm = 0; fm < 4; ++fm) {
            const int m = wid * 64 + fm * 16 + erow0;
#pragma unroll
            for (int r = 0; r < 4; ++r)
                out[(size_t)(m + r) * N + n] = acc[fm][fn][r] * s + bv;
        }
    }
}

extern "C" void kernel_launch(void* const* d_in, const int* in_sizes, int n_in,
                              void* d_out, int out_size, void* d_ws, size_t ws_size,
                              hipStream_t stream) {
    const float* x     = (const float*)d_in[0];
    const int*   w     = (const int*)d_in[1];
    const float* scale = (const float*)d_in[2];
    const float* bias  = (const float*)d_in[3];
    float* out = (float*)d_out;
    __bf16* xb = (__bf16*)d_ws;   // 2 MB scratch for bf16 x

    cvt_x_kernel<<<dim3(M * K / (256 * 4)), dim3(256), 0, stream>>>(x, xb);
    qlin_gemm<<<dim3(N / BN), dim3(256), 0, stream>>>(xb, w, scale, bias, out);
}

// Round 2
// 109.000 us; speedup vs baseline: 1.0044x; 1.0044x over previous
//
#include <hip/hip_runtime.h>
#include <hip/hip_bf16.h>
#include <stdint.h>

// QuantizedLinear: out[m][n] = (sum_k x[m][k]*W[n][k]) * scale + bias[n]
// M=256, K=4096, N=11008. W int32 holds int8 values -> exact in bf16;
// scale applied in epilogue so GEMM path is exact except x->bf16 rounding.
//
// Round-2 structure: A (x) fragments loaded global->reg double-buffered
// (x bf16 = 2MB, L2-resident; per-element consumed once -> LDS staging was
// pure overhead). Only B (W tile, 32x32) goes through LDS (shared by the
// block's 2 waves), reg-staged 2-deep with raw s_barrier + lgkmcnt(0) only:
// no vmcnt(0) drain, so all global prefetches stay in flight across barriers.

#define M 256
#define N 11008
#define K 4096
#define BM 128
#define BN 32
#define BK 32
#define NKT (K / BK)   // 128

typedef __bf16 bf16x8 __attribute__((ext_vector_type(8)));
typedef float  f32x4  __attribute__((ext_vector_type(4)));

// ---- pass 1: x f32 -> bf16 into workspace ----
__global__ void cvt_x_kernel(const float* __restrict__ x, __bf16* __restrict__ xb) {
    int i = (blockIdx.x * 256 + threadIdx.x) * 4;
    float4 v = *(const float4*)(x + i);
    union { __bf16 b[4]; uint2 u; } o;
    o.b[0] = (__bf16)v.x; o.b[1] = (__bf16)v.y;
    o.b[2] = (__bf16)v.z; o.b[3] = (__bf16)v.w;
    *(uint2*)(xb + i) = o.u;
}

// ---- pass 2: GEMM ----
// block = 128 threads (2 waves), wave w owns rows [mh*128 + w*64, +64) x 32 cols.
// grid = dim3(2, 344): m-half fastest so the 2 blocks sharing a W tile are
// dispatched adjacently (W row read lands in L2/L3 for the twin).
// LDS: B tile [32 rows][80B] bf16 (padded: 80 = 5*16 -> 16B-aligned rows,
// 2-way max bank aliasing on both b128 read and write), double buffered = 5KB.
__global__ __launch_bounds__(128, 4) void qlin_gemm(
    const __bf16* __restrict__ xb, const int* __restrict__ w,
    const float* __restrict__ scale, const float* __restrict__ bias,
    float* __restrict__ out) {

    __shared__ __align__(16) char bsm[2 * 2560];

    const int tid  = threadIdx.x;    // 0..127
    const int lane = tid & 63;
    const int wid  = tid >> 6;       // 0..1
    const int mh   = blockIdx.x;     // 0..1
    const int n0   = blockIdx.y * BN;

    f32x4 acc[4][2] = {};

    // A direct: af[fm] covers rows mh*128 + wid*64 + fm*16 + (lane&15),
    // k-slice (lane>>4)*8 .. +8 (16B load, 16B-aligned).
    const __bf16* a_base = xb + (size_t)(mh * BM + wid * 64 + (lane & 15)) * K + (lane >> 4) * 8;

    // B stage: thread t -> row t>>2 (0..31), chunk t&3 (8 ints = 32B -> 8 bf16 = 16B)
    const int brow = tid >> 2, bc = tid & 3;
    const int* w_base = w + (size_t)(n0 + brow) * K + bc * 8;
    const int b_wbyte = brow * 80 + bc * 16;
    // B frag read: fn -> row fn*16 + (lane&15), k-chunk lane>>4
    const int b_rbyte = (lane & 15) * 80 + (lane >> 4) * 16;

    auto loadA = [&](bf16x8 (&af)[4], int kt) {
        const __bf16* p = a_base + kt * BK;
#pragma unroll
        for (int fm = 0; fm < 4; ++fm)
            af[fm] = *(const bf16x8*)(p + fm * 16 * K);
    };
    auto loadB = [&](int4 (&r)[2], int kt) {
        const int* p = w_base + kt * BK;
        r[0] = *(const int4*)p;
        r[1] = *(const int4*)(p + 4);
    };
    auto writeB = [&](const int4 (&r)[2], int buf) {
        union { __bf16 b[8]; bf16x8 v; } t;
        t.b[0] = (__bf16)(float)r[0].x; t.b[1] = (__bf16)(float)r[0].y;
        t.b[2] = (__bf16)(float)r[0].z; t.b[3] = (__bf16)(float)r[0].w;
        t.b[4] = (__bf16)(float)r[1].x; t.b[5] = (__bf16)(float)r[1].y;
        t.b[6] = (__bf16)(float)r[1].z; t.b[7] = (__bf16)(float)r[1].w;
        *(bf16x8*)(bsm + buf * 2560 + b_wbyte) = t.v;
    };
    auto compute = [&](const bf16x8 (&af)[4], int buf) {
        const char* B = bsm + buf * 2560;
        bf16x8 b0 = *(const bf16x8*)(B + b_rbyte);
        bf16x8 b1 = *(const bf16x8*)(B + 1280 + b_rbyte);
#pragma unroll
        for (int fm = 0; fm < 4; ++fm) {
            acc[fm][0] = __builtin_amdgcn_mfma_f32_16x16x32_bf16(af[fm], b0, acc[fm][0], 0, 0, 0);
            acc[fm][1] = __builtin_amdgcn_mfma_f32_16x16x32_bf16(af[fm], b1, acc[fm][1], 0, 0, 0);
        }
    };

    bf16x8 afE[4], afO[4];
    int4 rBE[2], rBO[2];

    // prologue: tile 0 staged; B(1) prefetch left in flight across barrier
    loadA(afE, 0);
    loadB(rBE, 0);
    writeB(rBE, 0);          // compiler waits rBE arrival here only
    loadB(rBO, 1);
    asm volatile("s_waitcnt lgkmcnt(0)" ::: "memory");
    __builtin_amdgcn_s_barrier();

    for (int tp = 0; tp < NKT / 2; ++tp) {
        const int t0 = tp * 2;
        // even tile t0 (buf 0)
        {
            const int ka = (t0 + 1 < NKT) ? t0 + 1 : NKT - 1;
            const int kb = (t0 + 2 < NKT) ? t0 + 2 : NKT - 1;
            loadA(afO, ka);          // A(t0+1) -> regs, in flight during compute
            loadB(rBE, kb);          // B(t0+2) -> regs, 2-tile-deep pipeline
            compute(afE, 0);
            writeB(rBO, 1);          // B(t0+1) (loaded 1 iter ago) -> LDS buf1
            asm volatile("s_waitcnt lgkmcnt(0)" ::: "memory");
            __builtin_amdgcn_s_barrier();
        }
        // odd tile t0+1 (buf 1)
        {
            const int ka = (t0 + 2 < NKT) ? t0 + 2 : NKT - 1;
            const int kb = (t0 + 3 < NKT) ? t0 + 3 : NKT - 1;
            loadA(afE, ka);
            loadB(rBO, kb);
            compute(afO, 1);
            writeB(rBE, 0);
            asm volatile("s_waitcnt lgkmcnt(0)" ::: "memory");
            __builtin_amdgcn_s_barrier();
        }
    }

    // epilogue: D layout col=lane&15, row=(lane>>4)*4+reg (m89); y = acc*scale + bias
    const float s = scale[0];
    const int ecol  = lane & 15;
    const int erow0 = (lane >> 4) * 4;
#pragma unroll
    for (int fn = 0; fn < 2; ++fn) {
        const int n = n0 + fn * 16 + ecol;
        const float bv = bias[n];
#pragma unroll
        for (int fm = 0; fm < 4; ++fm) {
            const int m = mh * BM + wid * 64 + fm * 16 + erow0;
#pragma unroll
            for (int r = 0; r < 4; ++r)
                out[(size_t)(m + r) * N + n] = acc[fm][fn][r] * s + bv;
        }
    }
}

extern "C" void kernel_launch(void* const* d_in, const int* in_sizes, int n_in,
                              void* d_out, int out_size, void* d_ws, size_t ws_size,
                              hipStream_t stream) {
    const float* x     = (const float*)d_in[0];
    const int*   w     = (const int*)d_in[1];
    const float* scale = (const float*)d_in[2];
    const float* bias  = (const float*)d_in[3];
    float* out = (float*)d_out;
    __bf16* xb = (__bf16*)d_ws;   // 2 MB scratch for bf16 x

    cvt_x_kernel<<<dim3(M * K / (256 * 4)), dim3(256), 0, stream>>>(x, xb);
    qlin_gemm<<<dim3(2, N / BN), dim3(128), 0, stream>>>(xb, w, scale, bias, out);
}

// Round 3
// 87.178 us; speedup vs baseline: 1.2558x; 1.2503x over previous
//
#include <hip/hip_runtime.h>
#include <hip/hip_bf16.h>
#include <stdint.h>

// QuantizedLinear: out[m][n] = (sum_k x[m][k]*W[n][k]) * scale + bias[n]
// M=256, K=4096, N=11008. W int8-valued -> exact in bf16; scale/bias in f32 epilogue.
//
// R3: 4-wave blocks (BM=128, BN=32, BK=64), 688 blocks = 10.75 waves/CU.
// W: global->reg (4-slot named ring, loaded 3 tiles ahead) -> cvt -> LDS
// (2-slot ring, XOR-swizzled) -> ds_read_b128 frags. Load->use gap = 2 iters
// (~2000cy > HBM latency). Raw s_barrier + lgkmcnt(0) only; vmcnt never drained.
// A: pre-packed bf16 MFMA fragments in d_ws (L2-resident), 1KB coalesced
// wave loads, double-buffered 1 tile ahead.

#define MM 256
#define NN 11008
#define KK 4096
#define BM 128
#define BN 32
#define BK 64
#define NT (KK / BK)   // 64

typedef __bf16 bf16x8 __attribute__((ext_vector_type(8)));
typedef float  f32x4  __attribute__((ext_vector_type(4)));

// ---- pass 1: x f32 [256][4096] -> bf16 packed in MFMA-fragment order ----
// xf[(mb*128 + kb)*64 + l] = bf16x8 { x[mb*16 + (l&15)][kb*32 + (l>>4)*8 + j] }
__global__ void cvt_x_kernel(const float* __restrict__ x, bf16x8* __restrict__ xf) {
    int i  = blockIdx.x * 256 + threadIdx.x;   // 0..131071
    int l  = i & 63;
    int kb = (i >> 6) & 127;
    int mb = i >> 13;
    int m  = mb * 16 + (l & 15);
    int k  = kb * 32 + (l >> 4) * 8;
    const float* p = x + (size_t)m * KK + k;
    float4 v0 = *(const float4*)p;
    float4 v1 = *(const float4*)(p + 4);
    union { __bf16 b[8]; bf16x8 v; } t;
    t.b[0] = (__bf16)v0.x; t.b[1] = (__bf16)v0.y;
    t.b[2] = (__bf16)v0.z; t.b[3] = (__bf16)v0.w;
    t.b[4] = (__bf16)v1.x; t.b[5] = (__bf16)v1.y;
    t.b[6] = (__bf16)v1.z; t.b[7] = (__bf16)v1.w;
    xf[i] = t.v;
}

// ---- pass 2: GEMM ----
__global__ __launch_bounds__(256, 3) void qlin_gemm(
    const bf16x8* __restrict__ xf, const int* __restrict__ w,
    const float* __restrict__ scale, const float* __restrict__ bias,
    float* __restrict__ out) {

    __shared__ __align__(16) char bsm[2 * 4096];   // 2 slots x (32 rows x 128B)

    const int tid  = threadIdx.x;    // 0..255
    const int lane = tid & 63;
    const int wid  = tid >> 6;       // 0..3  (wave owns rows mh*128 + wid*32 .. +32)
    const int mh   = blockIdx.x;     // 0..1
    const int n0   = blockIdx.y * BN;

    // W staging: thread -> row (tid>>3) of 32, k-chunk (tid&7)*8 ints (32B -> 16B bf16)
    const int wrow = tid >> 3;
    const int wc   = tid & 7;
    const int* wbase = w + (size_t)(n0 + wrow) * KK + wc * 8;
    const int wdst = wrow * 128 + ((wc * 16) ^ ((wrow & 7) << 4));

    // B fragment read offsets (per ks, fn): row = fn*16 + (lane&15)
    int brd[2][2];
#pragma unroll
    for (int ks = 0; ks < 2; ++ks)
#pragma unroll
        for (int fn = 0; fn < 2; ++fn) {
            const int row = fn * 16 + (lane & 15);
            brd[ks][fn] = row * 128 + ((ks * 64 + (lane >> 4) * 16) ^ ((row & 7) << 4));
        }

    // A fragments: frag(fm, kb) at xf[((mh*8 + wid*2 + fm)*128 + kb)*64 + lane]
    const bf16x8* abase = xf + ((size_t)(mh * 8 + wid * 2) * 128) * 64 + lane;

    f32x4 acc[2][2] = {};

    int4 s0[2], s1[2], s2[2], s3[2];   // W(k) lives in slot k%4
    bf16x8 aA[2][2], aB[2][2];         // A double buffer [ks][fm]

    auto loadW = [&](int4 (&r)[2], int t) {
        const int* p = wbase + t * BK;
        r[0] = *(const int4*)p;
        r[1] = *(const int4*)(p + 4);
    };
    auto loadA = [&](bf16x8 (&a)[2][2], int t) {
#pragma unroll
        for (int ks = 0; ks < 2; ++ks)
#pragma unroll
            for (int fm = 0; fm < 2; ++fm)
                a[ks][fm] = abase[(size_t)(fm * 128 + t * 2 + ks) * 64];
    };
    auto writeW = [&](const int4 (&r)[2], int tdst) {
        union { __bf16 b[8]; bf16x8 v; } c;
        c.b[0] = (__bf16)(float)r[0].x; c.b[1] = (__bf16)(float)r[0].y;
        c.b[2] = (__bf16)(float)r[0].z; c.b[3] = (__bf16)(float)r[0].w;
        c.b[4] = (__bf16)(float)r[1].x; c.b[5] = (__bf16)(float)r[1].y;
        c.b[6] = (__bf16)(float)r[1].z; c.b[7] = (__bf16)(float)r[1].w;
        *(bf16x8*)(bsm + (tdst & 1) * 4096 + wdst) = c.v;
    };
    auto compute = [&](const bf16x8 (&a)[2][2], int t) {
        const char* B = bsm + (t & 1) * 4096;
#pragma unroll
        for (int ks = 0; ks < 2; ++ks) {
            bf16x8 bf0 = *(const bf16x8*)(B + brd[ks][0]);
            bf16x8 bf1 = *(const bf16x8*)(B + brd[ks][1]);
#pragma unroll
            for (int fm = 0; fm < 2; ++fm) {
                acc[fm][0] = __builtin_amdgcn_mfma_f32_16x16x32_bf16(a[ks][fm], bf0, acc[fm][0], 0, 0, 0);
                acc[fm][1] = __builtin_amdgcn_mfma_f32_16x16x32_bf16(a[ks][fm], bf1, acc[fm][1], 0, 0, 0);
            }
        }
    };

    // ---- prologue: W(0..2) in regs, W(0) staged to LDS slot 0, A(0) in regs ----
    loadW(s0, 0);
    loadW(s1, 1);
    loadW(s2, 2);
    loadA(aA, 0);
    writeW(s0, 0);
    asm volatile("s_waitcnt lgkmcnt(0)" ::: "memory");
    __builtin_amdgcn_s_barrier();
    __builtin_amdgcn_sched_barrier(0);

    // ---- main loop: iter t = {writeW(t+1); loadW(t+3); loadA(t+1); compute(t); barrier} ----
#define STEP(T, SWR, SLD, AC, AN)                                   \
    {                                                               \
        const int t_ = (T);                                         \
        writeW(SWR, t_ + 1);                                        \
        loadW(SLD, (t_ + 3 < NT) ? t_ + 3 : NT - 1);                \
        loadA(AN, (t_ + 1 < NT) ? t_ + 1 : NT - 1);                 \
        compute(AC, t_);                                            \
        asm volatile("s_waitcnt lgkmcnt(0)" ::: "memory");          \
        __builtin_amdgcn_s_barrier();                               \
        __builtin_amdgcn_sched_barrier(0);                          \
    }

    for (int tp = 0; tp < NT / 4; ++tp) {
        const int t0 = tp * 4;
        STEP(t0 + 0, s1, s3, aA, aB)   // write W(t+1)=s[1], load W(t+3)->s[3]
        STEP(t0 + 1, s2, s0, aB, aA)
        STEP(t0 + 2, s3, s1, aA, aB)
        STEP(t0 + 3, s0, s2, aB, aA)
    }
#undef STEP

    // ---- epilogue: D layout col=lane&15, row=(lane>>4)*4+r; y = acc*scale + bias ----
    const float sc = scale[0];
    const int ecol  = lane & 15;
    const int erow0 = (lane >> 4) * 4;
#pragma unroll
    for (int fn = 0; fn < 2; ++fn) {
        const int n = n0 + fn * 16 + ecol;
        const float bv = bias[n];
#pragma unroll
        for (int fm = 0; fm < 2; ++fm) {
            const int mrow = mh * BM + wid * 32 + fm * 16 + erow0;
#pragma unroll
            for (int r = 0; r < 4; ++r)
                out[(size_t)(mrow + r) * NN + n] = acc[fm][fn][r] * sc + bv;
        }
    }
}

extern "C" void kernel_launch(void* const* d_in, const int* in_sizes, int n_in,
                              void* d_out, int out_size, void* d_ws, size_t ws_size,
                              hipStream_t stream) {
    const float* x     = (const float*)d_in[0];
    const int*   wq    = (const int*)d_in[1];
    const float* scale = (const float*)d_in[2];
    const float* bias  = (const float*)d_in[3];
    float* out = (float*)d_out;
    bf16x8* xf = (bf16x8*)d_ws;   // 2 MB packed-A scratch

    cvt_x_kernel<<<dim3(MM * KK / (256 * 8)), dim3(256), 0, stream>>>(x, xf);
    qlin_gemm<<<dim3(2, NN / BN), dim3(256), 0, stream>>>(xf, wq, scale, bias, out);
}